// Round 10
// baseline (2073.748 us; speedup 1.0000x reference)
//
#include <hip/hip_runtime.h>
#include <math.h>

#define G 4
#define H 64
#define T 1000
#define B 32
#define ROWS (B*T)  // 32000

typedef _Float16 f16;
typedef _Float16 f16x2 __attribute__((ext_vector_type(2)));

#if defined(__has_builtin)
#if __has_builtin(__builtin_amdgcn_fdot2)
#define HAVE_FDOT2 1
#endif
#endif

__device__ __forceinline__ float dot2(f16x2 a, f16x2 b, float c) {
#ifdef HAVE_FDOT2
    return __builtin_amdgcn_fdot2(a, b, c, false);
#else
    return fmaf((float)a[0], (float)b[0], fmaf((float)a[1], (float)b[1], c));
#endif
}

__device__ __forceinline__ float sigm(float x) {
    return 1.f / (1.f + __expf(-x));
}
__device__ __forceinline__ float tanh_f(float x) {
    return 2.f / (1.f + __expf(-2.f * x)) - 1.f;
}

// ============================================================================
// Recurrence: ONE WAVE handles TWO sequences (same g -> shared weights).
// Lane c owns column c, all 4 gate rows, for BOTH seqs. The two seqs'
// dependency chains (dots -> act -> c/h -> LDS roundtrip) interleave inside
// the wave, filling each other's latency stalls (R9 showed 1 chain/SIMD
// leaves ~900cy/step of exposed latency). Zero barriers (same-wave LDS order).
// VGPR: wpk 128 (shared) + 2x(hpk 32 + p 8 + state) ~= 250 -> fits 256.
// ============================================================================
template<int LAYER>
__device__ void rec_wave2(const float* __restrict__ xp,     // (128, tcmax, 256)
                          const float* __restrict__ Whh,    // (G,256,64)
                          float* __restrict__ out,          // (B,T,256)
                          float* __restrict__ stateh, float* __restrict__ statec,
                          float* __restrict__ sums,         // [512] s|ss
                          int t0, int t1, int tcmax)
{
    __builtin_amdgcn_s_setprio(1);
    __shared__ __align__(16) _Float16 hx[4][2][64];
    const int wv = threadIdx.x >> 6;
    const int c  = threadIdx.x & 63;
    const int Wid = blockIdx.x * 4 + wv;     // 0..63
    const int g = Wid >> 4, b = Wid & 15;
    const int sqA = g * 32 + b;              // slot g*32+b
    const int sqB = sqA + 16;

    // shared weights: wpk[gt][k] = (W[row,2k], W[row,2k+1]) f16
    f16x2 wpk[4][32];
    #pragma unroll
    for (int gt = 0; gt < 4; ++gt) {
        const float2* wp = (const float2*)&Whh[(size_t)((g * 256 + gt * 64 + c) << 6)];
        #pragma unroll
        for (int k = 0; k < 32; ++k) {
            float2 v = wp[k];
            f16x2 r; r[0] = (f16)v.x; r[1] = (f16)v.y;
            wpk[gt][k] = r;
        }
    }

    f16x2 hA[32], hB[32];
    float cA, cB;
    if (t0 == 0) {
        #pragma unroll
        for (int k = 0; k < 32; ++k) {
            f16x2 z; z[0] = (f16)0.f; z[1] = (f16)0.f;
            hA[k] = z; hB[k] = z;
        }
        cA = 0.f; cB = 0.f;
    } else {
        const float2* shA = (const float2*)&stateh[sqA * 64];
        const float2* shB = (const float2*)&stateh[sqB * 64];
        #pragma unroll
        for (int k = 0; k < 32; ++k) {
            float2 va = shA[k], vb = shB[k];
            f16x2 ra; ra[0] = (f16)va.x; ra[1] = (f16)va.y;
            f16x2 rb; rb[0] = (f16)vb.x; rb[1] = (f16)vb.y;
            hA[k] = ra; hB[k] = rb;
        }
        cA = statec[sqA * 64 + c];
        cB = statec[sqB * 64 + c];
    }

    const float* xpA = xp + (size_t)sqA * tcmax * 256;
    const float* xpB = xp + (size_t)sqB * tcmax * 256;
    float pA[2][4], pB[2][4];
    #pragma unroll
    for (int j = 0; j < 2; ++j) {
        int tp = t0 + j; if (tp > t1 - 1) tp = t1 - 1;
        #pragma unroll
        for (int gt = 0; gt < 4; ++gt) {
            pA[j][gt] = xpA[(size_t)(tp - t0) * 256 + gt * 64 + c];
            pB[j][gt] = xpB[(size_t)(tp - t0) * 256 + gt * 64 + c];
        }
    }

    float sA = 0.f, ssA = 0.f, hlA = 0.f;
    float sB = 0.f, ssB = 0.f, hlB = 0.f;
    const int nsteps = t1 - t0;     // multiple of 4
    for (int s2 = 0; s2 < nsteps; s2 += 2) {
        #pragma unroll
        for (int j = 0; j < 2; ++j) {
            float preA[4], preB[4];
            // interleaved dual-seq dots: 8 independent chains (4 gates x 2 seqs)
            #pragma unroll
            for (int gt = 0; gt < 4; ++gt) {
                float a0 = 0.f, a1 = 0.f, b0 = 0.f, b1 = 0.f;
                #pragma unroll
                for (int k = 0; k < 32; k += 2) {
                    a0 = dot2(wpk[gt][k],     hA[k],     a0);
                    b0 = dot2(wpk[gt][k],     hB[k],     b0);
                    a1 = dot2(wpk[gt][k + 1], hA[k + 1], a1);
                    b1 = dot2(wpk[gt][k + 1], hB[k + 1], b1);
                }
                preA[gt] = (a0 + a1) + pA[j][gt];
                preB[gt] = (b0 + b1) + pB[j][gt];
            }
            // refill slot j (consumed 2 steps later; never drained — no barriers)
            {
                int tp = t0 + s2 + j + 2; if (tp > t1 - 1) tp = t1 - 1;
                #pragma unroll
                for (int gt = 0; gt < 4; ++gt) {
                    pA[j][gt] = xpA[(size_t)(tp - t0) * 256 + gt * 64 + c];
                    pB[j][gt] = xpB[(size_t)(tp - t0) * 256 + gt * 64 + c];
                }
            }
            float igA = sigm(preA[0]), igB = sigm(preB[0]);
            float fgA = sigm(preA[1]), fgB = sigm(preB[1]);
            float ggA = tanh_f(preA[2]), ggB = tanh_f(preB[2]);
            float ogA = sigm(preA[3]), ogB = sigm(preB[3]);
            cA = fmaf(fgA, cA, igA * ggA);
            cB = fmaf(fgB, cB, igB * ggB);
            float hAv = ogA * tanh_f(cA);
            float hBv = ogB * tanh_f(cB);
            int t = t0 + s2 + j;
            if (LAYER == 1) {
                out[((size_t)b * T + t) * 256 + c * 4 + g] = hAv;
                out[((size_t)(b + 16) * T + t) * 256 + c * 4 + g] = hBv;
            } else {
                out[((size_t)b * T + t) * 256 + g * 64 + c] = hAv;
                out[((size_t)(b + 16) * T + t) * 256 + g * 64 + c] = hBv;
            }
            sA += hAv; ssA = fmaf(hAv, hAv, ssA); hlA = hAv;
            sB += hBv; ssB = fmaf(hBv, hBv, ssB); hlB = hBv;
            // intra-wave h broadcast for both seqs (same-wave lgkmcnt order)
            hx[wv][0][c] = (f16)hAv;
            hx[wv][1][c] = (f16)hBv;
            const float4* rpA = (const float4*)&hx[wv][0][0];
            const float4* rpB = (const float4*)&hx[wv][1][0];
            #pragma unroll
            for (int q = 0; q < 8; ++q) {
                float4 va = rpA[q];
                float4 vb = rpB[q];
                hA[q * 4 + 0] = __builtin_bit_cast(f16x2, va.x);
                hA[q * 4 + 1] = __builtin_bit_cast(f16x2, va.y);
                hA[q * 4 + 2] = __builtin_bit_cast(f16x2, va.z);
                hA[q * 4 + 3] = __builtin_bit_cast(f16x2, va.w);
                hB[q * 4 + 0] = __builtin_bit_cast(f16x2, vb.x);
                hB[q * 4 + 1] = __builtin_bit_cast(f16x2, vb.y);
                hB[q * 4 + 2] = __builtin_bit_cast(f16x2, vb.z);
                hB[q * 4 + 3] = __builtin_bit_cast(f16x2, vb.w);
            }
        }
    }
    stateh[sqA * 64 + c] = hlA;
    stateh[sqB * 64 + c] = hlB;
    statec[sqA * 64 + c] = cA;
    statec[sqB * 64 + c] = cB;
    int f = (LAYER == 1) ? (c * 4 + g) : (g * 64 + c);   // same feature for A,B
    atomicAdd(&sums[f], sA + sB);
    atomicAdd(&sums[256 + f], ssA + ssB);
}

// ============================================================================
// Projection tile (256 threads): 64t x 256k for one (g,b,tt). k-cols per
// thread are tx+16q (stride 16) -> conflict-free (R8/R9 verified: 0 conflicts).
// ============================================================================
template<bool BN>
__device__ void proj_tile(int id,
                          const float* __restrict__ xin,
                          const float* __restrict__ Wih,
                          const float* __restrict__ bias,
                          const float* __restrict__ ac,
                          float* __restrict__ xp,
                          int t0, int tcn, int tcmax, int TT)
{
    __shared__ __align__(16) float xs[64][68];
    __shared__ __align__(16) float wsm[64][68];

    const int tt = id % TT; id /= TT;
    const int b = id & 31;
    const int g = id >> 5;
    const int tid = threadIdx.x;
    const int tx = tid & 15, ty = tid >> 4;

    #pragma unroll
    for (int j = 0; j < 4; ++j) {
        int idx = j * 1024 + tid * 4;
        int r = idx >> 6, ci = idx & 63;
        int tg = t0 + tt * 64 + r; if (tg > T - 1) tg = T - 1;
        float4 v = *(const float4*)&xin[((size_t)b * T + tg) * 256 + g * 64 + ci];
        if (BN) {
            float4 a4 = *(const float4*)&ac[g * 64 + ci];
            float4 c4 = *(const float4*)&ac[256 + g * 64 + ci];
            v.x = fmaf(v.x, a4.x, c4.x);
            v.y = fmaf(v.y, a4.y, c4.y);
            v.z = fmaf(v.z, a4.z, c4.z);
            v.w = fmaf(v.w, a4.w, c4.w);
        }
        *(float4*)&xs[r][ci] = v;
    }

    float* xpb = xp + (size_t)(g * 32 + b) * tcmax * 256;

    for (int kt = 0; kt < 4; ++kt) {
        __syncthreads();
        #pragma unroll
        for (int j = 0; j < 4; ++j) {
            int idx = j * 1024 + tid * 4;
            int r = idx >> 6, ci = idx & 63;
            float4 v = *(const float4*)&Wih[(size_t)((g * 256 + kt * 64 + r) << 6) + ci];
            *(float4*)&wsm[r][ci] = v;
        }
        __syncthreads();

        float acc[4][4] = {};   // acc[a=t-sub][q=k-sub]; k-col = kt*64+tx+16q
        #pragma unroll
        for (int i4 = 0; i4 < 16; ++i4) {
            float4 xv[4], wv[4];
            #pragma unroll
            for (int q = 0; q < 4; ++q) xv[q] = *(const float4*)&xs[ty * 4 + q][i4 * 4];
            #pragma unroll
            for (int q = 0; q < 4; ++q) wv[q] = *(const float4*)&wsm[tx + 16 * q][i4 * 4];
            #pragma unroll
            for (int a = 0; a < 4; ++a)
                #pragma unroll
                for (int q = 0; q < 4; ++q) {
                    acc[a][q] = fmaf(xv[a].x, wv[q].x, acc[a][q]);
                    acc[a][q] = fmaf(xv[a].y, wv[q].y, acc[a][q]);
                    acc[a][q] = fmaf(xv[a].z, wv[q].z, acc[a][q]);
                    acc[a][q] = fmaf(xv[a].w, wv[q].w, acc[a][q]);
                }
        }

        float bq[4];
        #pragma unroll
        for (int q = 0; q < 4; ++q) bq[q] = bias[g * 256 + kt * 64 + tx + 16 * q];
        #pragma unroll
        for (int a = 0; a < 4; ++a) {
            int tloc = tt * 64 + ty * 4 + a;
            if (tloc < tcn) {
                #pragma unroll
                for (int q = 0; q < 4; ++q)
                    xpb[(size_t)tloc * 256 + kt * 64 + tx + 16 * q] = acc[a][q] + bq[q];
            }
        }
    }
}

// ============================================================================
// Fused dispatch (256-thread blocks): 0..15 = rec (4 waves x 2 seqs = 8 seqs);
// 16.. = one proj tile each for the next chunk.
// ============================================================================
template<int LAYER, bool PBN>
__global__ __launch_bounds__(256, 1)
void fused3(const float* __restrict__ xpA, const float* __restrict__ Whh,
            float* __restrict__ out,
            float* __restrict__ stateh, float* __restrict__ statec,
            float* __restrict__ sums,
            int t0, int t1, int tcmax,
            const float* __restrict__ xin, const float* __restrict__ Wih,
            const float* __restrict__ bias, const float* __restrict__ acbn,
            float* __restrict__ xpB, int t0n, int tcnn, int TTn)
{
    if (blockIdx.x < 16) {
        rec_wave2<LAYER>(xpA, Whh, out, stateh, statec, sums, t0, t1, tcmax);
    } else {
        proj_tile<PBN>(blockIdx.x - 16, xin, Wih, bias, acbn, xpB,
                       t0n, tcnn, tcmax, TTn);
    }
}

// Standalone projection (first chunk of each layer).
template<bool BN>
__global__ __launch_bounds__(256)
void xp_proj(const float* __restrict__ xin, const float* __restrict__ Wih,
             const float* __restrict__ bias, const float* __restrict__ ac,
             float* __restrict__ xp, int t0, int tcn, int tcmax, int TT)
{
    proj_tile<BN>(blockIdx.x, xin, Wih, bias, ac, xp, t0, tcn, tcmax, TT);
}

// ============================================================================
// Fallback (proven round-1) fused rec kernel for tiny ws.
// ============================================================================
template<int LAYER>
__global__ __launch_bounds__(256, 1)
void rec_kernel(const float* __restrict__ xin,
                const float* __restrict__ Wih,
                const float* __restrict__ Whh,
                const float* __restrict__ bias,
                const float* __restrict__ bnac,
                float* __restrict__ out)
{
    const int g = blockIdx.x & 3;
    const int b = blockIdx.x >> 2;
    const int k = threadIdx.x;

    __shared__ __align__(16) float xsh[2][64];
    __shared__ __align__(16) float hsh[64];
    __shared__ __align__(16) float gsh[256];

    float wih[64], whh[64];
    {
        const float4* wi = (const float4*)(Wih + (size_t)(g * 256 + k) * 64);
        const float4* wh = (const float4*)(Whh + (size_t)(g * 256 + k) * 64);
        #pragma unroll
        for (int i = 0; i < 16; ++i) {
            float4 v = wi[i];
            wih[4*i] = v.x; wih[4*i+1] = v.y; wih[4*i+2] = v.z; wih[4*i+3] = v.w;
            float4 u = wh[i];
            whh[4*i] = u.x; whh[4*i+1] = u.y; whh[4*i+2] = u.z; whh[4*i+3] = u.w;
        }
    }
    const float bk = bias[g * 256 + k];
    const long rowbase = (long)b * T;
    const int  colbase = g * 64;

    float c = 0.f, af = 1.f, cf = 0.f;
    float xa = 0.f, xb = 0.f;

    if (k < 64) {
        if (LAYER == 2) { af = bnac[colbase + k]; cf = bnac[256 + colbase + k]; }
        hsh[k] = 0.f;
        float x0 = xin[(rowbase + 0) * 256 + colbase + k];
        xsh[0][k] = (LAYER == 2) ? fmaf(x0, af, cf) : x0;
        xa = xin[(rowbase + 1) * 256 + colbase + k];
        xb = xin[(rowbase + 2) * 256 + colbase + k];
    }
    __syncthreads();

    for (int t = 0; t < T; ++t) {
        const int cur = t & 1;
        float xn = 0.f;
        if (k < 64) {
            int tp = t + 3; if (tp > T - 1) tp = T - 1;
            xn = xin[(rowbase + tp) * 256 + colbase + k];
        }
        const float* xs = xsh[cur];
        float a0 = 0.f, a1 = 0.f, a2 = 0.f, a3 = 0.f;
        #pragma unroll
        for (int i = 0; i < 64; i += 4) {
            a0 = fmaf(wih[i],     xs[i],     a0);
            a1 = fmaf(wih[i + 1], xs[i + 1], a1);
            a2 = fmaf(wih[i + 2], xs[i + 2], a2);
            a3 = fmaf(wih[i + 3], xs[i + 3], a3);
        }
        #pragma unroll
        for (int jq = 0; jq < 64; jq += 4) {
            a0 = fmaf(whh[jq],     hsh[jq],     a0);
            a1 = fmaf(whh[jq + 1], hsh[jq + 1], a1);
            a2 = fmaf(whh[jq + 2], hsh[jq + 2], a2);
            a3 = fmaf(whh[jq + 3], hsh[jq + 3], a3);
        }
        const float acc = bk + ((a0 + a1) + (a2 + a3));
        const float act = (k >= 128 && k < 192) ? tanh_f(acc) : sigm(acc);
        gsh[k] = act;
        __syncthreads();

        if (k < 64) {
            const float ig = gsh[k];
            const float fg = gsh[64 + k];
            const float gg = gsh[128 + k];
            const float og = gsh[192 + k];
            c = fmaf(fg, c, ig * gg);
            const float h = og * tanh_f(c);
            hsh[k] = h;
            const long rrow = rowbase + t;
            if (LAYER == 1) out[rrow * 256 + k * 4 + g] = h;
            else            out[rrow * 256 + colbase + k] = h;
            xsh[cur ^ 1][k] = fmaf(xa, af, cf);
            xa = xb; xb = xn;
        }
        __syncthreads();
    }
}

// ============================================================================
// BN stats / apply
// ============================================================================
__global__ void zero_ws(float* sums, int n) {
    int i = blockIdx.x * blockDim.x + threadIdx.x;
    if (i < n) sums[i] = 0.f;
}

__global__ __launch_bounds__(256) void stats_reduce(const float* __restrict__ x,
                                                    float* __restrict__ sums)
{
    float s = 0.f, ss = 0.f;
    for (int r = blockIdx.x; r < ROWS; r += gridDim.x) {
        float v = x[(long)r * 256 + threadIdx.x];
        s += v;
        ss = fmaf(v, v, ss);
    }
    atomicAdd(&sums[threadIdx.x], s);
    atomicAdd(&sums[256 + threadIdx.x], ss);
}

__global__ void stats_finalize(const float* __restrict__ sums,
                               const float* __restrict__ gamma,
                               const float* __restrict__ beta,
                               float* __restrict__ ac)
{
    int f = threadIdx.x;
    const float invN = 1.f / (float)ROWS;
    float mean = sums[f] * invN;
    float var  = fmaf(-mean, mean, sums[256 + f] * invN);
    float a = gamma[f] * rsqrtf(var + 1e-5f);
    ac[f]       = a;
    ac[256 + f] = fmaf(-mean, a, beta[f]);
}

__global__ __launch_bounds__(256) void bn_apply(float* __restrict__ x,
                                                const float* __restrict__ ac)
{
    __shared__ float a_s[256], c_s[256];
    a_s[threadIdx.x] = ac[threadIdx.x];
    c_s[threadIdx.x] = ac[256 + threadIdx.x];
    __syncthreads();
    const long n4 = (long)ROWS * 64;
    for (long i = (long)blockIdx.x * blockDim.x + threadIdx.x; i < n4;
         i += (long)gridDim.x * blockDim.x) {
        float4 v = ((float4*)x)[i];
        int f0 = (int)((i * 4) & 255);
        v.x = fmaf(v.x, a_s[f0],     c_s[f0]);
        v.y = fmaf(v.y, a_s[f0 + 1], c_s[f0 + 1]);
        v.z = fmaf(v.z, a_s[f0 + 2], c_s[f0 + 2]);
        v.w = fmaf(v.w, a_s[f0 + 3], c_s[f0 + 3]);
        ((float4*)x)[i] = v;
    }
}

extern "C" void kernel_launch(void* const* d_in, const int* in_sizes, int n_in,
                              void* d_out, int out_size, void* d_ws, size_t ws_size,
                              hipStream_t stream)
{
    const float* inpt   = (const float*)d_in[0];
    const float* Wih1   = (const float*)d_in[1];
    const float* Whh1   = (const float*)d_in[2];
    const float* b1     = (const float*)d_in[3];
    const float* Wih2   = (const float*)d_in[4];
    const float* Whh2   = (const float*)d_in[5];
    const float* b2     = (const float*)d_in[6];
    const float* gamma1 = (const float*)d_in[7];
    const float* beta1  = (const float*)d_in[8];
    const float* gamma2 = (const float*)d_in[9];
    const float* beta2  = (const float*)d_in[10];
    float* out  = (float*)d_out;

    float* sums1 = (float*)d_ws;        // 512
    float* sums2 = sums1 + 512;         // 512
    float* acbn1 = sums2 + 512;         // 512
    float* acbn2 = acbn1 + 512;         // 512
    float* sth   = acbn2 + 512;         // 8192 (128*64)
    float* stc   = sth + 8192;          // 8192
    float* xpb   = stc + 8192;          // 2 chunk buffers

    const size_t fixedB = (size_t)(4 * 512 + 2 * 8192) * 4;  // 73728
    const long perT = 128L * 256L * 4L;                       // bytes per timestep
    long availPair = ((long)ws_size - (long)fixedB) / (2L * perT);

    // chunk plan: small head chunk (its projection is the only unhidden one)
    int chunks[8]; int nch = 0;
    if (availPair >= 436) {
        chunks[0] = 128; chunks[1] = 436; chunks[2] = 436; nch = 3;
    } else if (availPair >= 8) {
        int Tc = (int)(availPair & ~3L);
        int acc = 0;
        while (acc < T && nch < 8) {
            int c = T - acc; if (c > Tc) c = Tc;
            chunks[nch++] = c; acc += c;
        }
        if (acc < T) nch = 0;   // can't cover T in 8 chunks -> fallback
    }

    if (nch > 0) {
        int tcmax = 0;
        for (int i = 0; i < nch; ++i) if (chunks[i] > tcmax) tcmax = chunks[i];
        float* buf[2] = { xpb, xpb + (size_t)tcmax * 128 * 256 };
        zero_ws<<<4, 256, 0, stream>>>(sums1, 1024);   // sums1+sums2

        for (int layer = 1; layer <= 2; ++layer) {
            const float* xin  = (layer == 1) ? inpt : out;
            const float* Wih  = (layer == 1) ? Wih1 : Wih2;
            const float* Whh  = (layer == 1) ? Whh1 : Whh2;
            const float* bb   = (layer == 1) ? b1 : b2;
            float* sums       = (layer == 1) ? sums1 : sums2;

            int t0 = 0;
            int TT0 = (chunks[0] + 63) / 64;
            if (layer == 1)
                xp_proj<false><<<128 * TT0, 256, 0, stream>>>(
                    xin, Wih, bb, nullptr, buf[0], 0, chunks[0], tcmax, TT0);
            else
                xp_proj<true><<<128 * TT0, 256, 0, stream>>>(
                    xin, Wih, bb, acbn1, buf[0], 0, chunks[0], tcmax, TT0);

            for (int c = 0; c < nch; ++c) {
                int t1 = t0 + chunks[c];
                int t0n = t1;
                int tcnn = (c + 1 < nch) ? chunks[c + 1] : 0;
                int TTn = (tcnn + 63) / 64;
                int grid = 16 + 128 * TTn;
                if (layer == 1)
                    fused3<1, false><<<grid, 256, 0, stream>>>(
                        buf[c & 1], Whh, out, sth, stc, sums, t0, t1, tcmax,
                        xin, Wih, bb, nullptr, buf[(c + 1) & 1], t0n, tcnn, TTn);
                else
                    fused3<2, true><<<grid, 256, 0, stream>>>(
                        buf[c & 1], Whh, out, sth, stc, sums, t0, t1, tcmax,
                        xin, Wih, bb, acbn1, buf[(c + 1) & 1], t0n, tcnn, TTn);
                t0 = t1;
            }
            if (layer == 1)
                stats_finalize<<<1, 256, 0, stream>>>(sums1, gamma1, beta1, acbn1);
            else
                stats_finalize<<<1, 256, 0, stream>>>(sums2, gamma2, beta2, acbn2);
        }
        bn_apply<<<2048, 256, 0, stream>>>(out, acbn2);
    } else {
        // ---- fallback: round-1 monolithic path (ws only needs 8 KB)
        zero_ws<<<2, 256, 0, stream>>>(sums1, 512);
        rec_kernel<1><<<G * B, 256, 0, stream>>>(inpt, Wih1, Whh1, b1, nullptr, out);
        stats_reduce<<<256, 256, 0, stream>>>(out, sums1);
        stats_finalize<<<1, 256, 0, stream>>>(sums1, gamma1, beta1, acbn1);
        rec_kernel<2><<<G * B, 256, 0, stream>>>(out, Wih2, Whh2, b2, acbn1, out);
        zero_ws<<<2, 256, 0, stream>>>(sums2, 512);
        stats_reduce<<<256, 256, 0, stream>>>(out, sums2);
        stats_finalize<<<1, 256, 0, stream>>>(sums2, gamma2, beta2, acbn2);
        bn_apply<<<2048, 256, 0, stream>>>(out, acbn2);
    }
}

// Round 11
// 1379.225 us; speedup vs baseline: 1.5036x; 1.5036x over previous
//
#include <hip/hip_runtime.h>
#include <math.h>

#define G 4
#define H 64
#define T 1000
#define B 32
#define ROWS (B*T)  // 32000
#define SS 8        // xp LDS staging group size (steps)

typedef _Float16 f16;
typedef _Float16 f16x2 __attribute__((ext_vector_type(2)));

#if defined(__has_builtin)
#if __has_builtin(__builtin_amdgcn_fdot2)
#define HAVE_FDOT2 1
#endif
#endif

__device__ __forceinline__ float dot2(f16x2 a, f16x2 b, float c) {
#ifdef HAVE_FDOT2
    return __builtin_amdgcn_fdot2(a, b, c, false);
#else
    return fmaf((float)a[0], (float)b[0], fmaf((float)a[1], (float)b[1], c));
#endif
}

__device__ __forceinline__ float sigm(float x) {
    return 1.f / (1.f + __expf(-x));
}
__device__ __forceinline__ float tanh_f(float x) {
    return 2.f / (1.f + __expf(-2.f * x)) - 1.f;
}

typedef const __attribute__((address_space(1))) void gas_void;
typedef __attribute__((address_space(3))) void las_void;

// ============================================================================
// Recurrence: ONE WAVE per sequence, zero barriers (R9 structure, 244 VGPR,
// no spill). NEW vs R9: xp is staged through LDS in SS-step double-buffered
// groups via global_load_lds (wave-uniform base + lane*16 — exactly our
// layout; no VGPR cost). Inner loop reads xp with 4 conflict-free ds_read_b32
// -> NO per-step vmcnt dependence; one vmcnt(0) per SS steps (lead = SS step
// times >> HBM latency). Same-wave producer/consumer -> still barrier-free.
// ============================================================================
template<int LAYER>
__device__ void rec_wave4(const float* __restrict__ xp,     // (128, tcmax, 256)
                          const float* __restrict__ Whh,    // (G,256,64)
                          float* __restrict__ out,          // (B,T,256)
                          float* __restrict__ stateh, float* __restrict__ statec,
                          float* __restrict__ sums,         // [512] s|ss
                          int t0, int t1, int tcmax)
{
    __builtin_amdgcn_s_setprio(1);
    __shared__ __align__(16) float xbuf[2][SS][4][256];   // 64 KiB
    __shared__ __align__(16) _Float16 hx[4][64];
    const int wv = threadIdx.x >> 6;
    const int c  = threadIdx.x & 63;
    const int sq = blockIdx.x * 4 + wv;     // g*32+b
    const int g = sq >> 5, b = sq & 31;

    // pack weights into registers: wpk[gt][k] = (W[row,2k], W[row,2k+1]) f16
    f16x2 wpk[4][32];
    #pragma unroll
    for (int gt = 0; gt < 4; ++gt) {
        const float2* wp = (const float2*)&Whh[(size_t)((g * 256 + gt * 64 + c) << 6)];
        #pragma unroll
        for (int k = 0; k < 32; ++k) {
            float2 v = wp[k];
            f16x2 r; r[0] = (f16)v.x; r[1] = (f16)v.y;
            wpk[gt][k] = r;
        }
    }

    f16x2 hpk[32];
    float cst;
    if (t0 == 0) {
        #pragma unroll
        for (int k = 0; k < 32; ++k) { f16x2 z; z[0] = (f16)0.f; z[1] = (f16)0.f; hpk[k] = z; }
        cst = 0.f;
    } else {
        const float2* sh = (const float2*)&stateh[sq * 64];
        #pragma unroll
        for (int k = 0; k < 32; ++k) {
            float2 v = sh[k];
            f16x2 r; r[0] = (f16)v.x; r[1] = (f16)v.y;
            hpk[k] = r;
        }
        cst = statec[sq * 64 + c];
    }

    const float* xpb = xp + (size_t)sq * tcmax * 256;

    // stage group 0 (lane c supplies floats c*4..c*4+3 of each step-row;
    // global_load_lds writes LDS at base + lane*16 — exactly that layout)
    #pragma unroll
    for (int j = 0; j < SS; ++j) {
        const float* gsrc = xpb + (size_t)j * 256 + c * 4;
        __builtin_amdgcn_global_load_lds((gas_void*)gsrc,
                                         (las_void*)&xbuf[0][j][wv][0], 16, 0, 0);
    }
    asm volatile("s_waitcnt vmcnt(0)" ::: "memory");
    __builtin_amdgcn_sched_barrier(0);

    float st_s = 0.f, st_ss = 0.f, hl = 0.f;
    const int ngrp = (t1 - t0) / SS;   // chunk length is a multiple of SS
    for (int grp = 0; grp < ngrp; ++grp) {
        const int cur = grp & 1;
        // issue staging of next group into the other buffer (consumed after
        // the vmcnt(0) at the end of this group — ~SS step-times of lead)
        if (grp + 1 < ngrp) {
            const int lbase = (grp + 1) * SS;
            #pragma unroll
            for (int j = 0; j < SS; ++j) {
                const float* gsrc = xpb + (size_t)(lbase + j) * 256 + c * 4;
                __builtin_amdgcn_global_load_lds((gas_void*)gsrc,
                                                 (las_void*)&xbuf[cur ^ 1][j][wv][0],
                                                 16, 0, 0);
            }
        }
        #pragma unroll
        for (int j = 0; j < SS; ++j) {
            // xp from LDS (stride-4B across lanes -> conflict-free)
            float pj0 = xbuf[cur][j][wv][c];
            float pj1 = xbuf[cur][j][wv][64 + c];
            float pj2 = xbuf[cur][j][wv][128 + c];
            float pj3 = xbuf[cur][j][wv][192 + c];
            float pre[4];
            {
                float a0 = 0.f, a1 = 0.f;
                #pragma unroll
                for (int k = 0; k < 32; k += 2) {
                    a0 = dot2(wpk[0][k],     hpk[k],     a0);
                    a1 = dot2(wpk[0][k + 1], hpk[k + 1], a1);
                }
                pre[0] = (a0 + a1) + pj0;
            }
            {
                float a0 = 0.f, a1 = 0.f;
                #pragma unroll
                for (int k = 0; k < 32; k += 2) {
                    a0 = dot2(wpk[1][k],     hpk[k],     a0);
                    a1 = dot2(wpk[1][k + 1], hpk[k + 1], a1);
                }
                pre[1] = (a0 + a1) + pj1;
            }
            {
                float a0 = 0.f, a1 = 0.f;
                #pragma unroll
                for (int k = 0; k < 32; k += 2) {
                    a0 = dot2(wpk[2][k],     hpk[k],     a0);
                    a1 = dot2(wpk[2][k + 1], hpk[k + 1], a1);
                }
                pre[2] = (a0 + a1) + pj2;
            }
            {
                float a0 = 0.f, a1 = 0.f;
                #pragma unroll
                for (int k = 0; k < 32; k += 2) {
                    a0 = dot2(wpk[3][k],     hpk[k],     a0);
                    a1 = dot2(wpk[3][k + 1], hpk[k + 1], a1);
                }
                pre[3] = (a0 + a1) + pj3;
            }
            float ig = sigm(pre[0]);
            float fg = sigm(pre[1]);
            float gg = tanh_f(pre[2]);
            float og = sigm(pre[3]);
            cst = fmaf(fg, cst, ig * gg);
            float h = og * tanh_f(cst);
            int t = t0 + grp * SS + j;
            if (LAYER == 1) out[((size_t)b * T + t) * 256 + c * 4 + g] = h;
            else            out[((size_t)b * T + t) * 256 + g * 64 + c] = h;
            st_s += h;
            st_ss = fmaf(h, h, st_ss);
            hl = h;
            // intra-wave h broadcast; read back as float4, reinterpret f16x2
            hx[wv][c] = (f16)h;
            const float4* hp = (const float4*)&hx[wv][0];
            #pragma unroll
            for (int q = 0; q < 8; ++q) {
                float4 v = hp[q];
                hpk[q * 4 + 0] = __builtin_bit_cast(f16x2, v.x);
                hpk[q * 4 + 1] = __builtin_bit_cast(f16x2, v.y);
                hpk[q * 4 + 2] = __builtin_bit_cast(f16x2, v.z);
                hpk[q * 4 + 3] = __builtin_bit_cast(f16x2, v.w);
            }
        }
        // next group's staged data must have landed before we read it
        asm volatile("s_waitcnt vmcnt(0)" ::: "memory");
        __builtin_amdgcn_sched_barrier(0);
    }
    stateh[sq * 64 + c] = hl;
    statec[sq * 64 + c] = cst;
    int f = (LAYER == 1) ? (c * 4 + g) : (g * 64 + c);
    atomicAdd(&sums[f], st_s);
    atomicAdd(&sums[256 + f], st_ss);
}

// ============================================================================
// Projection tile (256 threads): 64t x 256k for one (g,b,tt). k-cols per
// thread are tx+16q (stride 16) -> conflict-free (R8/R9 verified).
// ============================================================================
template<bool BN>
__device__ void proj_tile(int id,
                          const float* __restrict__ xin,
                          const float* __restrict__ Wih,
                          const float* __restrict__ bias,
                          const float* __restrict__ ac,
                          float* __restrict__ xp,
                          int t0, int tcn, int tcmax, int TT)
{
    __shared__ __align__(16) float xs[64][68];
    __shared__ __align__(16) float wsm[64][68];

    const int tt = id % TT; id /= TT;
    const int b = id & 31;
    const int g = id >> 5;
    const int tid = threadIdx.x;
    const int tx = tid & 15, ty = tid >> 4;

    #pragma unroll
    for (int j = 0; j < 4; ++j) {
        int idx = j * 1024 + tid * 4;
        int r = idx >> 6, ci = idx & 63;
        int tg = t0 + tt * 64 + r; if (tg > T - 1) tg = T - 1;
        float4 v = *(const float4*)&xin[((size_t)b * T + tg) * 256 + g * 64 + ci];
        if (BN) {
            float4 a4 = *(const float4*)&ac[g * 64 + ci];
            float4 c4 = *(const float4*)&ac[256 + g * 64 + ci];
            v.x = fmaf(v.x, a4.x, c4.x);
            v.y = fmaf(v.y, a4.y, c4.y);
            v.z = fmaf(v.z, a4.z, c4.z);
            v.w = fmaf(v.w, a4.w, c4.w);
        }
        *(float4*)&xs[r][ci] = v;
    }

    float* xpb = xp + (size_t)(g * 32 + b) * tcmax * 256;

    for (int kt = 0; kt < 4; ++kt) {
        __syncthreads();
        #pragma unroll
        for (int j = 0; j < 4; ++j) {
            int idx = j * 1024 + tid * 4;
            int r = idx >> 6, ci = idx & 63;
            float4 v = *(const float4*)&Wih[(size_t)((g * 256 + kt * 64 + r) << 6) + ci];
            *(float4*)&wsm[r][ci] = v;
        }
        __syncthreads();

        float acc[4][4] = {};   // acc[a=t-sub][q=k-sub]; k-col = kt*64+tx+16q
        #pragma unroll
        for (int i4 = 0; i4 < 16; ++i4) {
            float4 xv[4], wv[4];
            #pragma unroll
            for (int q = 0; q < 4; ++q) xv[q] = *(const float4*)&xs[ty * 4 + q][i4 * 4];
            #pragma unroll
            for (int q = 0; q < 4; ++q) wv[q] = *(const float4*)&wsm[tx + 16 * q][i4 * 4];
            #pragma unroll
            for (int a = 0; a < 4; ++a)
                #pragma unroll
                for (int q = 0; q < 4; ++q) {
                    acc[a][q] = fmaf(xv[a].x, wv[q].x, acc[a][q]);
                    acc[a][q] = fmaf(xv[a].y, wv[q].y, acc[a][q]);
                    acc[a][q] = fmaf(xv[a].z, wv[q].z, acc[a][q]);
                    acc[a][q] = fmaf(xv[a].w, wv[q].w, acc[a][q]);
                }
        }

        float bq[4];
        #pragma unroll
        for (int q = 0; q < 4; ++q) bq[q] = bias[g * 256 + kt * 64 + tx + 16 * q];
        #pragma unroll
        for (int a = 0; a < 4; ++a) {
            int tloc = tt * 64 + ty * 4 + a;
            if (tloc < tcn) {
                #pragma unroll
                for (int q = 0; q < 4; ++q)
                    xpb[(size_t)tloc * 256 + kt * 64 + tx + 16 * q] = acc[a][q] + bq[q];
            }
        }
    }
}

// ============================================================================
// Fused dispatch (256-thread blocks): 0..31 = rec (4 waves = 4 seqs each);
// 32.. = one proj tile each for the next chunk.
// ============================================================================
template<int LAYER, bool PBN>
__global__ __launch_bounds__(256, 1)
void fused3(const float* __restrict__ xpA, const float* __restrict__ Whh,
            float* __restrict__ out,
            float* __restrict__ stateh, float* __restrict__ statec,
            float* __restrict__ sums,
            int t0, int t1, int tcmax,
            const float* __restrict__ xin, const float* __restrict__ Wih,
            const float* __restrict__ bias, const float* __restrict__ acbn,
            float* __restrict__ xpB, int t0n, int tcnn, int TTn)
{
    if (blockIdx.x < 32) {
        rec_wave4<LAYER>(xpA, Whh, out, stateh, statec, sums, t0, t1, tcmax);
    } else {
        proj_tile<PBN>(blockIdx.x - 32, xin, Wih, bias, acbn, xpB,
                       t0n, tcnn, tcmax, TTn);
    }
}

// Standalone projection (first chunk of each layer).
template<bool BN>
__global__ __launch_bounds__(256)
void xp_proj(const float* __restrict__ xin, const float* __restrict__ Wih,
             const float* __restrict__ bias, const float* __restrict__ ac,
             float* __restrict__ xp, int t0, int tcn, int tcmax, int TT)
{
    proj_tile<BN>(blockIdx.x, xin, Wih, bias, ac, xp, t0, tcn, tcmax, TT);
}

// ============================================================================
// Fallback (proven round-1) fused rec kernel for tiny ws.
// ============================================================================
template<int LAYER>
__global__ __launch_bounds__(256, 1)
void rec_kernel(const float* __restrict__ xin,
                const float* __restrict__ Wih,
                const float* __restrict__ Whh,
                const float* __restrict__ bias,
                const float* __restrict__ bnac,
                float* __restrict__ out)
{
    const int g = blockIdx.x & 3;
    const int b = blockIdx.x >> 2;
    const int k = threadIdx.x;

    __shared__ __align__(16) float xsh[2][64];
    __shared__ __align__(16) float hsh[64];
    __shared__ __align__(16) float gsh[256];

    float wih[64], whh[64];
    {
        const float4* wi = (const float4*)(Wih + (size_t)(g * 256 + k) * 64);
        const float4* wh = (const float4*)(Whh + (size_t)(g * 256 + k) * 64);
        #pragma unroll
        for (int i = 0; i < 16; ++i) {
            float4 v = wi[i];
            wih[4*i] = v.x; wih[4*i+1] = v.y; wih[4*i+2] = v.z; wih[4*i+3] = v.w;
            float4 u = wh[i];
            whh[4*i] = u.x; whh[4*i+1] = u.y; whh[4*i+2] = u.z; whh[4*i+3] = u.w;
        }
    }
    const float bk = bias[g * 256 + k];
    const long rowbase = (long)b * T;
    const int  colbase = g * 64;

    float c = 0.f, af = 1.f, cf = 0.f;
    float xa = 0.f, xb = 0.f;

    if (k < 64) {
        if (LAYER == 2) { af = bnac[colbase + k]; cf = bnac[256 + colbase + k]; }
        hsh[k] = 0.f;
        float x0 = xin[(rowbase + 0) * 256 + colbase + k];
        xsh[0][k] = (LAYER == 2) ? fmaf(x0, af, cf) : x0;
        xa = xin[(rowbase + 1) * 256 + colbase + k];
        xb = xin[(rowbase + 2) * 256 + colbase + k];
    }
    __syncthreads();

    for (int t = 0; t < T; ++t) {
        const int cur = t & 1;
        float xn = 0.f;
        if (k < 64) {
            int tp = t + 3; if (tp > T - 1) tp = T - 1;
            xn = xin[(rowbase + tp) * 256 + colbase + k];
        }
        const float* xs = xsh[cur];
        float a0 = 0.f, a1 = 0.f, a2 = 0.f, a3 = 0.f;
        #pragma unroll
        for (int i = 0; i < 64; i += 4) {
            a0 = fmaf(wih[i],     xs[i],     a0);
            a1 = fmaf(wih[i + 1], xs[i + 1], a1);
            a2 = fmaf(wih[i + 2], xs[i + 2], a2);
            a3 = fmaf(wih[i + 3], xs[i + 3], a3);
        }
        #pragma unroll
        for (int jq = 0; jq < 64; jq += 4) {
            a0 = fmaf(whh[jq],     hsh[jq],     a0);
            a1 = fmaf(whh[jq + 1], hsh[jq + 1], a1);
            a2 = fmaf(whh[jq + 2], hsh[jq + 2], a2);
            a3 = fmaf(whh[jq + 3], hsh[jq + 3], a3);
        }
        const float acc = bk + ((a0 + a1) + (a2 + a3));
        const float act = (k >= 128 && k < 192) ? tanh_f(acc) : sigm(acc);
        gsh[k] = act;
        __syncthreads();

        if (k < 64) {
            const float ig = gsh[k];
            const float fg = gsh[64 + k];
            const float gg = gsh[128 + k];
            const float og = gsh[192 + k];
            c = fmaf(fg, c, ig * gg);
            const float h = og * tanh_f(c);
            hsh[k] = h;
            const long rrow = rowbase + t;
            if (LAYER == 1) out[rrow * 256 + k * 4 + g] = h;
            else            out[rrow * 256 + colbase + k] = h;
            xsh[cur ^ 1][k] = fmaf(xa, af, cf);
            xa = xb; xb = xn;
        }
        __syncthreads();
    }
}

// ============================================================================
// BN stats / apply
// ============================================================================
__global__ void zero_ws(float* sums, int n) {
    int i = blockIdx.x * blockDim.x + threadIdx.x;
    if (i < n) sums[i] = 0.f;
}

__global__ __launch_bounds__(256) void stats_reduce(const float* __restrict__ x,
                                                    float* __restrict__ sums)
{
    float s = 0.f, ss = 0.f;
    for (int r = blockIdx.x; r < ROWS; r += gridDim.x) {
        float v = x[(long)r * 256 + threadIdx.x];
        s += v;
        ss = fmaf(v, v, ss);
    }
    atomicAdd(&sums[threadIdx.x], s);
    atomicAdd(&sums[256 + threadIdx.x], ss);
}

__global__ void stats_finalize(const float* __restrict__ sums,
                               const float* __restrict__ gamma,
                               const float* __restrict__ beta,
                               float* __restrict__ ac)
{
    int f = threadIdx.x;
    const float invN = 1.f / (float)ROWS;
    float mean = sums[f] * invN;
    float var  = fmaf(-mean, mean, sums[256 + f] * invN);
    float a = gamma[f] * rsqrtf(var + 1e-5f);
    ac[f]       = a;
    ac[256 + f] = fmaf(-mean, a, beta[f]);
}

__global__ __launch_bounds__(256) void bn_apply(float* __restrict__ x,
                                                const float* __restrict__ ac)
{
    __shared__ float a_s[256], c_s[256];
    a_s[threadIdx.x] = ac[threadIdx.x];
    c_s[threadIdx.x] = ac[256 + threadIdx.x];
    __syncthreads();
    const long n4 = (long)ROWS * 64;
    for (long i = (long)blockIdx.x * blockDim.x + threadIdx.x; i < n4;
         i += (long)gridDim.x * blockDim.x) {
        float4 v = ((float4*)x)[i];
        int f0 = (int)((i * 4) & 255);
        v.x = fmaf(v.x, a_s[f0],     c_s[f0]);
        v.y = fmaf(v.y, a_s[f0 + 1], c_s[f0 + 1]);
        v.z = fmaf(v.z, a_s[f0 + 2], c_s[f0 + 2]);
        v.w = fmaf(v.w, a_s[f0 + 3], c_s[f0 + 3]);
        ((float4*)x)[i] = v;
    }
}

extern "C" void kernel_launch(void* const* d_in, const int* in_sizes, int n_in,
                              void* d_out, int out_size, void* d_ws, size_t ws_size,
                              hipStream_t stream)
{
    const float* inpt   = (const float*)d_in[0];
    const float* Wih1   = (const float*)d_in[1];
    const float* Whh1   = (const float*)d_in[2];
    const float* b1     = (const float*)d_in[3];
    const float* Wih2   = (const float*)d_in[4];
    const float* Whh2   = (const float*)d_in[5];
    const float* b2     = (const float*)d_in[6];
    const float* gamma1 = (const float*)d_in[7];
    const float* beta1  = (const float*)d_in[8];
    const float* gamma2 = (const float*)d_in[9];
    const float* beta2  = (const float*)d_in[10];
    float* out  = (float*)d_out;

    float* sums1 = (float*)d_ws;        // 512
    float* sums2 = sums1 + 512;         // 512
    float* acbn1 = sums2 + 512;         // 512
    float* acbn2 = acbn1 + 512;         // 512
    float* sth   = acbn2 + 512;         // 8192 (128*64)
    float* stc   = sth + 8192;          // 8192
    float* xpb   = stc + 8192;          // 2 chunk buffers

    const size_t fixedB = (size_t)(4 * 512 + 2 * 8192) * 4;  // 73728
    const long perT = 128L * 256L * 4L;                       // bytes per timestep
    long availPair = ((long)ws_size - (long)fixedB) / (2L * perT);

    // chunk plan: multiples of SS; small head chunk (only unhidden projection)
    int chunks[8]; int nch = 0;
    if (availPair >= 440) {
        chunks[0] = 128; chunks[1] = 440; chunks[2] = 432; nch = 3;
    } else if (availPair >= SS) {
        int Tc = (int)(availPair & ~(long)(SS - 1));
        int acc = 0;
        while (acc < T && nch < 8) {
            int c = T - acc; if (c > Tc) c = Tc;
            chunks[nch++] = c; acc += c;   // T=1000 is a multiple of 8
        }
        if (acc < T) nch = 0;
    }

    if (nch > 0) {
        int tcmax = 0;
        for (int i = 0; i < nch; ++i) if (chunks[i] > tcmax) tcmax = chunks[i];
        float* buf[2] = { xpb, xpb + (size_t)tcmax * 128 * 256 };
        zero_ws<<<4, 256, 0, stream>>>(sums1, 1024);   // sums1+sums2

        for (int layer = 1; layer <= 2; ++layer) {
            const float* xin  = (layer == 1) ? inpt : out;
            const float* Wih  = (layer == 1) ? Wih1 : Wih2;
            const float* Whh  = (layer == 1) ? Whh1 : Whh2;
            const float* bb   = (layer == 1) ? b1 : b2;
            float* sums       = (layer == 1) ? sums1 : sums2;

            int t0 = 0;
            int TT0 = (chunks[0] + 63) / 64;
            if (layer == 1)
                xp_proj<false><<<128 * TT0, 256, 0, stream>>>(
                    xin, Wih, bb, nullptr, buf[0], 0, chunks[0], tcmax, TT0);
            else
                xp_proj<true><<<128 * TT0, 256, 0, stream>>>(
                    xin, Wih, bb, acbn1, buf[0], 0, chunks[0], tcmax, TT0);

            for (int c = 0; c < nch; ++c) {
                int t1 = t0 + chunks[c];
                int t0n = t1;
                int tcnn = (c + 1 < nch) ? chunks[c + 1] : 0;
                int TTn = (tcnn + 63) / 64;
                int grid = 32 + 128 * TTn;
                if (layer == 1)
                    fused3<1, false><<<grid, 256, 0, stream>>>(
                        buf[c & 1], Whh, out, sth, stc, sums, t0, t1, tcmax,
                        xin, Wih, bb, nullptr, buf[(c + 1) & 1], t0n, tcnn, TTn);
                else
                    fused3<2, true><<<grid, 256, 0, stream>>>(
                        buf[c & 1], Whh, out, sth, stc, sums, t0, t1, tcmax,
                        xin, Wih, bb, acbn1, buf[(c + 1) & 1], t0n, tcnn, TTn);
                t0 = t1;
            }
            if (layer == 1)
                stats_finalize<<<1, 256, 0, stream>>>(sums1, gamma1, beta1, acbn1);
            else
                stats_finalize<<<1, 256, 0, stream>>>(sums2, gamma2, beta2, acbn2);
        }
        bn_apply<<<2048, 256, 0, stream>>>(out, acbn2);
    } else {
        // ---- fallback: round-1 monolithic path (ws only needs 8 KB)
        zero_ws<<<2, 256, 0, stream>>>(sums1, 512);
        rec_kernel<1><<<G * B, 256, 0, stream>>>(inpt, Wih1, Whh1, b1, nullptr, out);
        stats_reduce<<<256, 256, 0, stream>>>(out, sums1);
        stats_finalize<<<1, 256, 0, stream>>>(sums1, gamma1, beta1, acbn1);
        rec_kernel<2><<<G * B, 256, 0, stream>>>(out, Wih2, Whh2, b2, acbn1, out);
        zero_ws<<<2, 256, 0, stream>>>(sums2, 512);
        stats_reduce<<<256, 256, 0, stream>>>(out, sums2);
        stats_finalize<<<1, 256, 0, stream>>>(sums2, gamma2, beta2, acbn2);
        bn_apply<<<2048, 256, 0, stream>>>(out, acbn2);
    }
}